// Round 11
// baseline (494.864 us; speedup 1.0000x reference)
//
#include <hip/hip_runtime.h>
#include <math.h>

namespace {
constexpr int kH = 256;
constexpr int kL = 4;
constexpr int kAtomDim = 100;
constexpr int kB = 128;
constexpr int kNN = 32;
constexpr int kGS = 8;
constexpr int kN = kB * kNN;       // 4096
constexpr int kE = kB * kNN * kNN; // 131072
constexpr int kDinE = 581;
constexpr int kKF = 96;            // padded feature K (69 -> 96)
constexpr float kTwoPi = 6.28318530717958647692f;

typedef __bf16 bf16x8 __attribute__((ext_vector_type(8)));
typedef float  f32x4  __attribute__((ext_vector_type(4)));

__device__ __forceinline__ float fsilu(float x) {
    return x * __builtin_amdgcn_rcpf(1.0f + __expf(-x));
}

// ---------------- per-graph lattice: ltl = expm(S)^T expm(S) ----------------
__global__ void lattice_kernel(const float* __restrict__ lattices,
                               const float* __restrict__ k_mean,
                               const float* __restrict__ k_std,
                               const float* __restrict__ k_mask,
                               const float* __restrict__ k_bias,
                               float* __restrict__ ltl) {
    int b = threadIdx.x;
    if (b >= kB) return;
    double y[6];
    for (int k = 0; k < 6; ++k) {
        double v = (double)lattices[b * 6 + k] * (double)k_std[k] + (double)k_mean[k];
        y[k] = v * (double)k_mask[k] + (double)k_bias[k];
    }
    double A[9] = { y[0], y[3], y[4],
                    y[3], y[1], y[5],
                    y[4], y[5], y[2] };
    double nrm = 0.0;
    for (int i = 0; i < 3; ++i) {
        double r = fabs(A[i*3+0]) + fabs(A[i*3+1]) + fabs(A[i*3+2]);
        nrm = fmax(nrm, r);
    }
    int s = 0;
    while (nrm > 0.25 && s < 40) { nrm *= 0.5; s++; }
    double sc = 1.0;
    for (int i = 0; i < s; ++i) sc *= 0.5;
    for (int i = 0; i < 9; ++i) A[i] *= sc;
    double T[9]    = {1,0,0, 0,1,0, 0,0,1};
    double term[9] = {1,0,0, 0,1,0, 0,0,1};
    for (int it = 1; it <= 18; ++it) {
        double nt[9];
        double inv = 1.0 / (double)it;
        for (int i = 0; i < 3; ++i)
            for (int j = 0; j < 3; ++j) {
                double acc = 0.0;
                for (int k = 0; k < 3; ++k) acc += term[i*3+k] * A[k*3+j];
                nt[i*3+j] = acc * inv;
            }
        for (int i = 0; i < 9; ++i) { term[i] = nt[i]; T[i] += nt[i]; }
    }
    for (int q = 0; q < s; ++q) {
        double nt[9];
        for (int i = 0; i < 3; ++i)
            for (int j = 0; j < 3; ++j) {
                double acc = 0.0;
                for (int k = 0; k < 3; ++k) acc += T[i*3+k] * T[k*3+j];
                nt[i*3+j] = acc;
            }
        for (int i = 0; i < 9; ++i) T[i] = nt[i];
    }
    for (int i = 0; i < 3; ++i)
        for (int k = 0; k < 3; ++k) {
            double acc = 0.0;
            for (int j = 0; j < 3; ++j) acc += T[j*3+i] * T[j*3+k];
            ltl[b*9 + i*3 + k] = (float)acc;
        }
}

// ------- per-edge geometric features, bf16, padded to 96 ---------------------
__global__ void feats_bf_kernel(const float* __restrict__ frac,
                                const float* __restrict__ lattices,
                                const float* __restrict__ ltl,
                                __bf16* __restrict__ out) {
    int e = blockIdx.x * blockDim.x + threadIdx.x;
    if (e >= kE) return;
    int g = e >> 10;
    int src = (g << 5) + ((e >> 5) & 31);
    int dst = (g << 5) + (e & 31);
    float d[3];
    #pragma unroll
    for (int c = 0; c < 3; ++c) {
        float delta = frac[dst*3 + c] - frac[src*3 + c];
        d[c] = delta - rintf(delta);
    }
    __attribute__((aligned(16))) __bf16 f[kKF];
    #pragma unroll
    for (int k = 0; k < 6; ++k) f[k] = (__bf16)lattices[g*6 + k];
    #pragma unroll
    for (int c = 0; c < 3; ++c) {
        float th = d[c] * kTwoPi;
        float s1 = sinf(th), c1 = cosf(th);
        float sk = 0.0f, ck = 1.0f;
        f[6  + c*10] = (__bf16)0.0f;
        f[36 + c*10] = (__bf16)1.0f;
        #pragma unroll
        for (int fr = 1; fr < 10; ++fr) {
            float ns = sk*c1 + ck*s1;
            float nc = ck*c1 - sk*s1;
            sk = ns; ck = nc;
            f[6  + c*10 + fr] = (__bf16)sk;
            f[36 + c*10 + fr] = (__bf16)ck;
        }
    }
    float v0 = ltl[g*9+0]*d[0] + ltl[g*9+1]*d[1] + ltl[g*9+2]*d[2];
    float v1 = ltl[g*9+3]*d[0] + ltl[g*9+4]*d[1] + ltl[g*9+5]*d[2];
    float v2 = ltl[g*9+6]*d[0] + ltl[g*9+7]*d[1] + ltl[g*9+8]*d[2];
    float nr = sqrtf(v0*v0 + v1*v1 + v2*v2) + 1e-6f;
    f[66] = (__bf16)(v0/nr); f[67] = (__bf16)(v1/nr); f[68] = (__bf16)(v2/nr);
    #pragma unroll
    for (int k = 69; k < kKF; ++k) f[k] = (__bf16)0.0f;
    uint4* dstp = (uint4*)(out + (size_t)e * kKF);
    const uint4* srcp = (const uint4*)f;
    #pragma unroll
    for (int i = 0; i < kKF/8; ++i) dstp[i] = srcp[i];
}

// ---------------- one merged weight/input conversion kernel ----------------
constexpr int kW1abN = 4*512*256;   // 524288
constexpr int kW1cN  = 4*256*kKF;   // 98304
constexpr int kW2bN  = 4*256*256;   // 262144
constexpr int kNw1N  = 4*256*512;   // 524288
constexpr int kNw2N  = 4*256*256;   // 262144
constexpr int kAtN   = kN*128;      // 524288
constexpr int kEmbwN = 256*128;     // 32768
constexpr int kLatwN = 256*384;     // 98304
constexpr int kConvTotal = kW1abN + kW1cN + kW2bN + kNw1N + kNw2N + kAtN + kEmbwN + kLatwN;

__global__ void conv_all(const float* __restrict__ edge_w1, const float* __restrict__ edge_w2,
                         const float* __restrict__ node_w1, const float* __restrict__ node_w2,
                         const float* __restrict__ atom, const float* __restrict__ emb_w,
                         const float* __restrict__ latent_w,
                         __bf16* __restrict__ w1ab, __bf16* __restrict__ w1c,
                         __bf16* __restrict__ w2b, __bf16* __restrict__ nw1b,
                         __bf16* __restrict__ nw2b, __bf16* __restrict__ at_bf,
                         __bf16* __restrict__ embwb, __bf16* __restrict__ latwb) {
    int i = blockIdx.x * 256 + threadIdx.x;
    if (i < kW1abN) {
        int l = i >> 17, rem = i & 131071, r = rem >> 8, k = rem & 255;
        float v = (r < 256) ? edge_w1[((size_t)(l*256 + r))*kDinE + k]
                            : edge_w1[((size_t)(l*256 + (r-256)))*kDinE + 256 + k];
        w1ab[i] = (__bf16)v;
        return;
    }
    i -= kW1abN;
    if (i < kW1cN) {
        int l = i / (256*kKF), rem = i - l*256*kKF, n = rem / kKF, k = rem - n*kKF;
        w1c[i] = (__bf16)((k < 69) ? edge_w1[((size_t)(l*256 + n))*kDinE + 512 + k] : 0.0f);
        return;
    }
    i -= kW1cN;
    if (i < kW2bN) { w2b[i] = (__bf16)edge_w2[i]; return; }
    i -= kW2bN;
    if (i < kNw1N) { nw1b[i] = (__bf16)node_w1[i]; return; }
    i -= kNw1N;
    if (i < kNw2N) { nw2b[i] = (__bf16)node_w2[i]; return; }
    i -= kNw2N;
    if (i < kAtN) {
        int n = i >> 7, k = i & 127;
        at_bf[i] = (__bf16)((k < kAtomDim) ? atom[(size_t)n*kAtomDim + k] : 0.0f);
        return;
    }
    i -= kAtN;
    if (i < kEmbwN) {
        int n = i >> 7, k = i & 127;
        embwb[i] = (__bf16)((k < kAtomDim) ? emb_w[(size_t)n*kAtomDim + k] : 0.0f);
        return;
    }
    i -= kEmbwN;
    if (i < kLatwN) { latwb[i] = (__bf16)latent_w[i]; return; }
}

__global__ void temb_kernel(const float* __restrict__ t, __bf16* __restrict__ tecat) {
    int g = blockIdx.x;
    int tid = threadIdx.x;  // 128
    float tf = expf(-logf(10000.0f) * (float)(tid & 63) / 64.0f);
    float ta = t[g] * tf;
    float v = (tid < 64) ? cosf(ta) : sinf(ta);   // cos first
    __bf16 bv = (__bf16)v;
    #pragma unroll
    for (int nl = 0; nl < kNN; ++nl)
        tecat[((size_t)(g*kNN + nl))*384 + 256 + tid] = bv;
}

// ---------------- 64x64-tile bf16 GEMM: C = A[M][lda] @ W[N][ldw]^T ----------------
// EPI 0: Sb/D bf16 split (N=512): n<256 -> outbf = bf16(acc+bias), else outbf2 = bf16(acc)
// EPI 2: outbf = bf16(silu(acc+bias))             (stride ldo)
// EPI 3: h += silu(acc+bias); write h fp32 + hcat bf16
// EPI 4: outbf = bf16(acc+bias)                   (stride ldo)
// EPI 5: h = acc+bias (init); write h fp32 + hcat bf16
template<int K, int EPI>
__global__ __launch_bounds__(256) void gemm64(
        const __bf16* __restrict__ A, int lda,
        const __bf16* __restrict__ W, int ldw,
        const float* __restrict__ bias,
        __bf16* __restrict__ outbf, int ldo,
        __bf16* __restrict__ outbf2,
        float* __restrict__ hmaster, __bf16* __restrict__ hcat) {
    constexpr int NC = K / 32;
    __shared__ __bf16 As[2][64*40];
    __shared__ __bf16 Bs[2][64*40];
    int tid = threadIdx.x;
    int lane = tid & 63;
    int wid = tid >> 6;
    int wm = wid >> 1, wn = wid & 1;
    int r16 = lane & 15, g4 = lane >> 4;
    int mbase = blockIdx.x * 64;
    int nbase = blockIdx.y * 64;
    int srow = tid >> 2, sseg = tid & 3;
    const __bf16* agp = A + (size_t)(mbase + srow)*lda + sseg*8;
    const __bf16* wgp = W + (size_t)(nbase + srow)*ldw + sseg*8;
    int woff = srow*40 + sseg*8;

    f32x4 acc[2][2] = {};
    uint4 ra, rb;
    ra = *(const uint4*)(agp);
    rb = *(const uint4*)(wgp);
    *(uint4*)&As[0][woff] = ra;
    *(uint4*)&Bs[0][woff] = rb;
    __syncthreads();
    for (int c = 0; c < NC; ++c) {
        int cur = c & 1;
        if (c + 1 < NC) {
            ra = *(const uint4*)(agp + (c+1)*32);
            rb = *(const uint4*)(wgp + (c+1)*32);
        }
        bf16x8 af[2], bfg[2];
        #pragma unroll
        for (int mt = 0; mt < 2; ++mt)
            af[mt] = *(const bf16x8*)&As[cur][(wm*32 + mt*16 + r16)*40 + g4*8];
        #pragma unroll
        for (int nt = 0; nt < 2; ++nt)
            bfg[nt] = *(const bf16x8*)&Bs[cur][(wn*32 + nt*16 + r16)*40 + g4*8];
        #pragma unroll
        for (int mt = 0; mt < 2; ++mt)
            #pragma unroll
            for (int nt = 0; nt < 2; ++nt)
                acc[mt][nt] = __builtin_amdgcn_mfma_f32_16x16x32_bf16(af[mt], bfg[nt], acc[mt][nt], 0, 0, 0);
        if (c + 1 < NC) {
            int nxt = cur ^ 1;
            *(uint4*)&As[nxt][woff] = ra;
            *(uint4*)&Bs[nxt][woff] = rb;
        }
        __syncthreads();
    }
    #pragma unroll
    for (int mt = 0; mt < 2; ++mt)
        #pragma unroll
        for (int nt = 0; nt < 2; ++nt) {
            int n = nbase + wn*32 + nt*16 + r16;
            #pragma unroll
            for (int r = 0; r < 4; ++r) {
                int m = mbase + wm*32 + mt*16 + g4*4 + r;
                float v = acc[mt][nt][r];
                if (EPI == 0) {
                    if (n < 256) outbf[(size_t)m*256 + n] = (__bf16)(v + bias[n]);
                    else         outbf2[(size_t)m*256 + (n - 256)] = (__bf16)v;
                } else if (EPI == 2) {
                    outbf[(size_t)m*ldo + n] = (__bf16)fsilu(v + bias[n]);
                } else if (EPI == 3) {
                    float hv = hmaster[(size_t)m*256 + n] + fsilu(v + bias[n]);
                    hmaster[(size_t)m*256 + n] = hv;
                    hcat[(size_t)m*512 + n] = (__bf16)hv;
                } else if (EPI == 4) {
                    outbf[(size_t)m*ldo + n] = (__bf16)(v + bias[n]);
                } else if (EPI == 5) {
                    float hv = v + bias[n];
                    hmaster[(size_t)m*256 + n] = hv;
                    hcat[(size_t)m*512 + n] = (__bf16)hv;
                }
            }
        }
}

// ------------- fused edge kernel: block = 64 edges (2 srcs), BK=64, 2 barriers/chunk ----
// Per nc (64-k2 chunk, 4 iters):
//   [top barrier] issue W2 staging -> phase1 (reg-only: feats x direct-global w1c)
//   -> A-build (reads Ds/Ss LDS, writes As_) -> [combined barrier: As_ + W2s ready]
//   -> phase2 (32 MFMA). W2 staging latency hides under phase1 + A-build.
// LDS 64KB -> 2 blocks/CU.
__global__ __launch_bounds__(256, 2) void fused_edge(
        const __bf16* __restrict__ Sb, const __bf16* __restrict__ Dq,
        const __bf16* __restrict__ fb, const __bf16* __restrict__ w1c,
        const __bf16* __restrict__ w2, const float* __restrict__ b2,
        __bf16* __restrict__ hcat) {
    __shared__ __bf16 Ds[32][264];    // 16.9 KB
    __shared__ __bf16 Ss[2][264];     // 1.06 KB
    __shared__ __bf16 W2s[256][72];   // 36.9 KB (64-wide k2 chunk)
    __shared__ __bf16 As_[64][72];    // 9.2 KB

    int tid = threadIdx.x;
    int lane = tid & 63;
    int w = tid >> 6;
    int sl = w >> 1;                  // phase2: src local (0/1)
    int ch = w & 1;                   // phase2: col half
    int r16 = lane & 15, g4 = lane >> 4;
    int ebase = blockIdx.x * 64;
    int graph = ebase >> 10;
    int s0 = ebase >> 5;              // srcs s0, s0+1

    // feats rows for this wave's 16 A-build rows (edges w*16 .. w*16+15)
    bf16x8 fReg[3];
    {
        const __bf16* fp = fb + (size_t)(ebase + w*16 + r16)*kKF + g4*8;
        fReg[0] = *(const bf16x8*)(fp);
        fReg[1] = *(const bf16x8*)(fp + 32);
        fReg[2] = *(const bf16x8*)(fp + 64);
    }
    { // Ds: 32 rows x 256 bf16
        int dl = tid >> 3, seg = tid & 7;
        const uint4* src = (const uint4*)(Dq + (size_t)(graph*32 + dl)*256 + seg*32);
        uint4* dst = (uint4*)&Ds[dl][seg*32];
        dst[0] = src[0]; dst[1] = src[1]; dst[2] = src[2]; dst[3] = src[3];
    }
    if (tid < 64) { // Ss: 2 rows x 256 bf16
        int slr = tid >> 5, c8 = (tid & 31)*8;
        *(uint4*)&Ss[slr][c8] = *(const uint4*)(Sb + (size_t)(s0 + slr)*256 + c8);
    }
    __syncthreads();                  // Ds/Ss ready

    f32x4 acc2[2][8] = {};
    for (int nc = 0; nc < 4; ++nc) {
        if (nc) __syncthreads();      // prev phase2 done with As_/W2s
        // issue W2 k2-chunk staging [256][64]; latency hides under phase1/A-build
        #pragma unroll
        for (int p = 0; p < 8; ++p) {
            int row = (tid >> 3) + p*32;
            int q = tid & 7;
            *(uint4*)&W2s[row][q*8] =
                *(const uint4*)(w2 + (size_t)row*256 + nc*64 + q*8);
        }
        // phase1 + A-build per 16-col tile (4 tiles = 64 cols)
        #pragma unroll
        for (int ct = 0; ct < 4; ++ct) {
            f32x4 acc1 = {};
            #pragma unroll
            for (int kc = 0; kc < 3; ++kc) {
                bf16x8 bg = *(const bf16x8*)(w1c +
                    (size_t)(nc*64 + ct*16 + r16)*kKF + kc*32 + g4*8);
                acc1 = __builtin_amdgcn_mfma_f32_16x16x32_bf16(fReg[kc], bg, acc1, 0, 0, 0);
            }
            int n_loc = ct*16 + r16;
            int n = nc*64 + n_loc;
            #pragma unroll
            for (int r = 0; r < 4; ++r) {
                int e_loc = w*16 + g4*4 + r;
                float v = acc1[r] + (float)Ss[e_loc >> 5][n] + (float)Ds[e_loc & 31][n];
                As_[e_loc][n_loc] = (__bf16)fsilu(v);
            }
        }
        __syncthreads();              // As_ + W2s ready

        // phase2: src sl's 32 rows x ch's 128 cols, k2 = 64
        bf16x8 am[2][2];
        #pragma unroll
        for (int half = 0; half < 2; ++half)
            #pragma unroll
            for (int ks = 0; ks < 2; ++ks)
                am[half][ks] = *(const bf16x8*)&As_[sl*32 + half*16 + r16][ks*32 + g4*8];
        #pragma unroll
        for (int nt = 0; nt < 8; ++nt) {
            #pragma unroll
            for (int ks = 0; ks < 2; ++ks) {
                bf16x8 bv = *(const bf16x8*)&W2s[ch*128 + nt*16 + r16][ks*32 + g4*8];
                acc2[0][nt] = __builtin_amdgcn_mfma_f32_16x16x32_bf16(am[0][ks], bv, acc2[0][nt], 0, 0, 0);
                acc2[1][nt] = __builtin_amdgcn_mfma_f32_16x16x32_bf16(am[1][ks], bv, acc2[1][nt], 0, 0, 0);
            }
        }
    }

    // epilogue: mean over src's 32 edges of silu(acc2 + b2)
    const float inv32 = 1.0f / 32.0f;
    #pragma unroll
    for (int nt = 0; nt < 8; ++nt) {
        int col = ch*128 + nt*16 + r16;
        float bb = b2[col];
        float p = 0.f;
        #pragma unroll
        for (int r = 0; r < 4; ++r)
            p += fsilu(acc2[0][nt][r] + bb) + fsilu(acc2[1][nt][r] + bb);
        p += __shfl_xor(p, 16);
        p += __shfl_xor(p, 32);
        if (lane < 16)
            hcat[(size_t)(s0 + sl)*512 + 256 + col] = (__bf16)(p * inv32);
    }
}

// ---------------- heads ----------------
__global__ void coord_equiv_kernel(const float* __restrict__ h,
                                   const float* __restrict__ coord_w,
                                   const float* __restrict__ G,
                                   const int* __restrict__ invp,
                                   float* __restrict__ out_x) {
    int b = blockIdx.x;
    int tid = threadIdx.x; // 128
    __shared__ float cd[kNN][4];
    if (tid < kNN*3) {
        int nl = tid / 3, j = tid - nl*3;
        const float* hr = h + (size_t)(b*kNN + nl)*kH;
        const float* wr = coord_w + (size_t)j*kH;
        float acc = 0.f;
        #pragma unroll 4
        for (int k = 0; k < kH; ++k) acc += hr[k]*wr[k];
        cd[nl][j] = acc;
    }
    __syncthreads();
    if (tid < kNN*3) {
        int nl = tid / 3, j = tid - nl*3;
        float acc = 0.f;
        for (int g = 0; g < kGS; ++g) {
            int bg = b*kGS + g;
            int p = invp[bg*kNN + nl];
            const float* Gr = G + (size_t)bg*16 + j*4;
            acc += cd[p][0]*Gr[0] + cd[p][1]*Gr[1] + cd[p][2]*Gr[2] + Gr[3];
        }
        out_x[(size_t)(b*kNN + nl)*3 + j] = acc * (1.0f/kGS);
    }
}

__global__ void graphfeat_kernel(const float* __restrict__ h,
                                 const float* __restrict__ lattice_w,
                                 float* __restrict__ out_lat) {
    int g = blockIdx.x;
    int c = threadIdx.x;
    __shared__ float gf[kH];
    float s = 0.f;
    for (int nl = 0; nl < kNN; ++nl) s += h[(size_t)(g*kNN + nl)*kH + c];
    gf[c] = s * (1.0f/kNN);
    __syncthreads();
    if (c < 6) {
        const float* wr = lattice_w + (size_t)c*kH;
        float acc = 0.f;
        #pragma unroll 4
        for (int k = 0; k < kH; ++k) acc += gf[k]*wr[k];
        out_lat[g*6 + c] = acc;
    }
}

} // namespace

extern "C" void kernel_launch(void* const* d_in, const int* in_sizes, int n_in,
                              void* d_out, int out_size, void* d_ws, size_t ws_size,
                              hipStream_t stream) {
    (void)in_sizes; (void)n_in; (void)out_size; (void)ws_size;
    const float* t         = (const float*)d_in[0];
    const float* atom      = (const float*)d_in[1];
    const float* frac      = (const float*)d_in[2];
    const float* lattices  = (const float*)d_in[3];
    const float* G         = (const float*)d_in[4];
    const float* k_mean    = (const float*)d_in[5];
    const float* k_std     = (const float*)d_in[6];
    const float* k_mask    = (const float*)d_in[7];
    const float* k_bias    = (const float*)d_in[8];
    const float* emb_w     = (const float*)d_in[9];
    const float* emb_b     = (const float*)d_in[10];
    const float* latent_w  = (const float*)d_in[11];
    const float* latent_b  = (const float*)d_in[12];
    const float* edge_w1   = (const float*)d_in[13];
    const float* edge_b1   = (const float*)d_in[14];
    const float* edge_w2   = (const float*)d_in[15];
    const float* edge_b2   = (const float*)d_in[16];
    const float* node_w1   = (const float*)d_in[17];
    const float* node_b1   = (const float*)d_in[18];
    const float* node_w2   = (const float*)d_in[19];
    const float* node_b2   = (const float*)d_in[20];
    const float* coord_w   = (const float*)d_in[21];
    const float* lattice_w = (const float*)d_in[22];
    const int*   invp      = (const int*)d_in[25];

    float* out_x   = (float*)d_out;            // [4096,3]
    float* out_lat = (float*)d_out + kN*3;     // [128,6]

    char* base = (char*)d_ws;
    size_t off = 0;
    auto carve = [&](size_t bytes) { char* p = base + off; off += bytes; return p; };
    float*  ltl    = (float*)carve(8192);
    float*  h      = (float*)carve(4194304);          // [4096][256] fp32
    __bf16* Sbuf   = (__bf16*)carve(2097152);         // [4096][256] bf16: S + b1
    __bf16* Dbuf   = (__bf16*)carve(2097152);         // [4096][256] bf16: D
    __bf16* hcat   = (__bf16*)carve(4194304);         // [4096][512] bf16: [h | agg]
    __bf16* t1     = (__bf16*)carve(2097152);         // [4096][256] bf16
    __bf16* fb     = (__bf16*)carve(25165824);        // feats bf16 [131072][96]
    __bf16* w1ab   = (__bf16*)carve(1048576);         // [L][512][256]
    __bf16* w1c    = (__bf16*)carve(262144);          // [L][256][96]
    __bf16* w2b    = (__bf16*)carve(524288);          // [L][256][256]
    __bf16* nw1b   = (__bf16*)carve(1048576);         // [L][256][512]
    __bf16* nw2b   = (__bf16*)carve(524288);          // [L][256][256]
    __bf16* at_bf  = (__bf16*)carve(1048576);         // [4096][128] atom bf16 padded
    __bf16* embwb  = (__bf16*)carve(65536);           // [256][128]
    __bf16* latwb  = (__bf16*)carve(196608);          // [256][384]
    __bf16* tecat  = (__bf16*)carve(3145728);         // [4096][384]: [h0 | temb]

    lattice_kernel<<<1, 128, 0, stream>>>(lattices, k_mean, k_std, k_mask, k_bias, ltl);
    feats_bf_kernel<<<kE/256, 256, 0, stream>>>(frac, lattices, ltl, fb);
    conv_all<<<(kConvTotal + 255)/256, 256, 0, stream>>>(
        edge_w1, edge_w2, node_w1, node_w2, atom, emb_w, latent_w,
        w1ab, w1c, w2b, nw1b, nw2b, at_bf, embwb, latwb);
    temb_kernel<<<kB, 128, 0, stream>>>(t, tecat);

    // embed GEMM1: h0 = at_bf[4096,128] @ embwb[256,128]^T + emb_b -> tecat[:, :256]
    gemm64<128, 4><<<dim3(64, 4), 256, 0, stream>>>(
        at_bf, 128, embwb, 128, emb_b,
        tecat, 384, nullptr, nullptr, nullptr);
    // embed GEMM2: h = tecat[4096,384] @ latwb[256,384]^T + latent_b -> h fp32 + hcat bf16
    gemm64<384, 5><<<dim3(64, 4), 256, 0, stream>>>(
        tecat, 384, latwb, 384, latent_b,
        nullptr, 0, nullptr, h, hcat);

    for (int l = 0; l < kL; ++l) {
        // S/D: [4096,256(of 512)] @ w1ab[512][256]^T -> bf16 Sbuf(+b1), Dbuf
        gemm64<256, 0><<<dim3(64, 8), 256, 0, stream>>>(
            hcat, 512, w1ab + (size_t)l*512*256, 256,
            edge_b1 + l*256, Sbuf, 256, Dbuf, nullptr, nullptr);
        // fused edge path: Fproj + A-build + GEMM2 + scatter-mean agg
        fused_edge<<<2048, 256, 0, stream>>>(
            Sbuf, Dbuf, fb, w1c + (size_t)l*256*kKF,
            w2b + (size_t)l*256*256, edge_b2 + l*256, hcat);
        // node MLP
        gemm64<512, 2><<<dim3(64, 4), 256, 0, stream>>>(
            hcat, 512, nw1b + (size_t)l*256*512, 512,
            node_b1 + l*256, t1, 256, nullptr, nullptr, nullptr);
        gemm64<256, 3><<<dim3(64, 4), 256, 0, stream>>>(
            t1, 256, nw2b + (size_t)l*256*256, 256,
            node_b2 + l*256, nullptr, 0, nullptr, h, hcat);
    }
    coord_equiv_kernel<<<kB, 128, 0, stream>>>(h, coord_w, G, invp, out_x);
    graphfeat_kernel<<<kB, 256, 0, stream>>>(h, lattice_w, out_lat);
}

// Round 12
// 450.163 us; speedup vs baseline: 1.0993x; 1.0993x over previous
//
#include <hip/hip_runtime.h>
#include <math.h>

namespace {
constexpr int kH = 256;
constexpr int kL = 4;
constexpr int kAtomDim = 100;
constexpr int kB = 128;
constexpr int kNN = 32;
constexpr int kGS = 8;
constexpr int kN = kB * kNN;       // 4096
constexpr int kE = kB * kNN * kNN; // 131072
constexpr int kDinE = 581;
constexpr int kKF = 96;            // padded feature K (69 -> 96)
constexpr float kTwoPi = 6.28318530717958647692f;

typedef __bf16 bf16x8 __attribute__((ext_vector_type(8)));
typedef float  f32x4  __attribute__((ext_vector_type(4)));

__device__ __forceinline__ float fsilu(float x) {
    return x * __builtin_amdgcn_rcpf(1.0f + __expf(-x));
}

// ---------------- per-graph lattice: ltl = expm(S)^T expm(S) ----------------
__global__ void lattice_kernel(const float* __restrict__ lattices,
                               const float* __restrict__ k_mean,
                               const float* __restrict__ k_std,
                               const float* __restrict__ k_mask,
                               const float* __restrict__ k_bias,
                               float* __restrict__ ltl) {
    int b = threadIdx.x;
    if (b >= kB) return;
    double y[6];
    for (int k = 0; k < 6; ++k) {
        double v = (double)lattices[b * 6 + k] * (double)k_std[k] + (double)k_mean[k];
        y[k] = v * (double)k_mask[k] + (double)k_bias[k];
    }
    double A[9] = { y[0], y[3], y[4],
                    y[3], y[1], y[5],
                    y[4], y[5], y[2] };
    double nrm = 0.0;
    for (int i = 0; i < 3; ++i) {
        double r = fabs(A[i*3+0]) + fabs(A[i*3+1]) + fabs(A[i*3+2]);
        nrm = fmax(nrm, r);
    }
    int s = 0;
    while (nrm > 0.25 && s < 40) { nrm *= 0.5; s++; }
    double sc = 1.0;
    for (int i = 0; i < s; ++i) sc *= 0.5;
    for (int i = 0; i < 9; ++i) A[i] *= sc;
    double T[9]    = {1,0,0, 0,1,0, 0,0,1};
    double term[9] = {1,0,0, 0,1,0, 0,0,1};
    for (int it = 1; it <= 18; ++it) {
        double nt[9];
        double inv = 1.0 / (double)it;
        for (int i = 0; i < 3; ++i)
            for (int j = 0; j < 3; ++j) {
                double acc = 0.0;
                for (int k = 0; k < 3; ++k) acc += term[i*3+k] * A[k*3+j];
                nt[i*3+j] = acc * inv;
            }
        for (int i = 0; i < 9; ++i) { term[i] = nt[i]; T[i] += nt[i]; }
    }
    for (int q = 0; q < s; ++q) {
        double nt[9];
        for (int i = 0; i < 3; ++i)
            for (int j = 0; j < 3; ++j) {
                double acc = 0.0;
                for (int k = 0; k < 3; ++k) acc += T[i*3+k] * T[k*3+j];
                nt[i*3+j] = acc;
            }
        for (int i = 0; i < 9; ++i) T[i] = nt[i];
    }
    for (int i = 0; i < 3; ++i)
        for (int k = 0; k < 3; ++k) {
            double acc = 0.0;
            for (int j = 0; j < 3; ++j) acc += T[j*3+i] * T[j*3+k];
            ltl[b*9 + i*3 + k] = (float)acc;
        }
}

// ------- per-edge geometric features, bf16, padded to 96 ---------------------
__global__ void feats_bf_kernel(const float* __restrict__ frac,
                                const float* __restrict__ lattices,
                                const float* __restrict__ ltl,
                                __bf16* __restrict__ out) {
    int e = blockIdx.x * blockDim.x + threadIdx.x;
    if (e >= kE) return;
    int g = e >> 10;
    int src = (g << 5) + ((e >> 5) & 31);
    int dst = (g << 5) + (e & 31);
    float d[3];
    #pragma unroll
    for (int c = 0; c < 3; ++c) {
        float delta = frac[dst*3 + c] - frac[src*3 + c];
        d[c] = delta - rintf(delta);
    }
    __attribute__((aligned(16))) __bf16 f[kKF];
    #pragma unroll
    for (int k = 0; k < 6; ++k) f[k] = (__bf16)lattices[g*6 + k];
    #pragma unroll
    for (int c = 0; c < 3; ++c) {
        float th = d[c] * kTwoPi;
        float s1 = sinf(th), c1 = cosf(th);
        float sk = 0.0f, ck = 1.0f;
        f[6  + c*10] = (__bf16)0.0f;
        f[36 + c*10] = (__bf16)1.0f;
        #pragma unroll
        for (int fr = 1; fr < 10; ++fr) {
            float ns = sk*c1 + ck*s1;
            float nc = ck*c1 - sk*s1;
            sk = ns; ck = nc;
            f[6  + c*10 + fr] = (__bf16)sk;
            f[36 + c*10 + fr] = (__bf16)ck;
        }
    }
    float v0 = ltl[g*9+0]*d[0] + ltl[g*9+1]*d[1] + ltl[g*9+2]*d[2];
    float v1 = ltl[g*9+3]*d[0] + ltl[g*9+4]*d[1] + ltl[g*9+5]*d[2];
    float v2 = ltl[g*9+6]*d[0] + ltl[g*9+7]*d[1] + ltl[g*9+8]*d[2];
    float nr = sqrtf(v0*v0 + v1*v1 + v2*v2) + 1e-6f;
    f[66] = (__bf16)(v0/nr); f[67] = (__bf16)(v1/nr); f[68] = (__bf16)(v2/nr);
    #pragma unroll
    for (int k = 69; k < kKF; ++k) f[k] = (__bf16)0.0f;
    uint4* dstp = (uint4*)(out + (size_t)e * kKF);
    const uint4* srcp = (const uint4*)f;
    #pragma unroll
    for (int i = 0; i < kKF/8; ++i) dstp[i] = srcp[i];
}

// ---------------- one merged weight/input conversion kernel ----------------
constexpr int kW1abN = 4*512*256;   // 524288
constexpr int kW1cN  = 4*256*kKF;   // 98304
constexpr int kW2bN  = 4*256*256;   // 262144
constexpr int kNw1N  = 4*256*512;   // 524288
constexpr int kNw2N  = 4*256*256;   // 262144
constexpr int kAtN   = kN*128;      // 524288
constexpr int kEmbwN = 256*128;     // 32768
constexpr int kLatwN = 256*384;     // 98304
constexpr int kConvTotal = kW1abN + kW1cN + kW2bN + kNw1N + kNw2N + kAtN + kEmbwN + kLatwN;

__global__ void conv_all(const float* __restrict__ edge_w1, const float* __restrict__ edge_w2,
                         const float* __restrict__ node_w1, const float* __restrict__ node_w2,
                         const float* __restrict__ atom, const float* __restrict__ emb_w,
                         const float* __restrict__ latent_w,
                         __bf16* __restrict__ w1ab, __bf16* __restrict__ w1c,
                         __bf16* __restrict__ w2b, __bf16* __restrict__ nw1b,
                         __bf16* __restrict__ nw2b, __bf16* __restrict__ at_bf,
                         __bf16* __restrict__ embwb, __bf16* __restrict__ latwb) {
    int i = blockIdx.x * 256 + threadIdx.x;
    if (i < kW1abN) {
        int l = i >> 17, rem = i & 131071, r = rem >> 8, k = rem & 255;
        float v = (r < 256) ? edge_w1[((size_t)(l*256 + r))*kDinE + k]
                            : edge_w1[((size_t)(l*256 + (r-256)))*kDinE + 256 + k];
        w1ab[i] = (__bf16)v;
        return;
    }
    i -= kW1abN;
    if (i < kW1cN) {
        int l = i / (256*kKF), rem = i - l*256*kKF, n = rem / kKF, k = rem - n*kKF;
        w1c[i] = (__bf16)((k < 69) ? edge_w1[((size_t)(l*256 + n))*kDinE + 512 + k] : 0.0f);
        return;
    }
    i -= kW1cN;
    if (i < kW2bN) { w2b[i] = (__bf16)edge_w2[i]; return; }
    i -= kW2bN;
    if (i < kNw1N) { nw1b[i] = (__bf16)node_w1[i]; return; }
    i -= kNw1N;
    if (i < kNw2N) { nw2b[i] = (__bf16)node_w2[i]; return; }
    i -= kNw2N;
    if (i < kAtN) {
        int n = i >> 7, k = i & 127;
        at_bf[i] = (__bf16)((k < kAtomDim) ? atom[(size_t)n*kAtomDim + k] : 0.0f);
        return;
    }
    i -= kAtN;
    if (i < kEmbwN) {
        int n = i >> 7, k = i & 127;
        embwb[i] = (__bf16)((k < kAtomDim) ? emb_w[(size_t)n*kAtomDim + k] : 0.0f);
        return;
    }
    i -= kEmbwN;
    if (i < kLatwN) { latwb[i] = (__bf16)latent_w[i]; return; }
}

__global__ void temb_kernel(const float* __restrict__ t, __bf16* __restrict__ tecat) {
    int g = blockIdx.x;
    int tid = threadIdx.x;  // 128
    float tf = expf(-logf(10000.0f) * (float)(tid & 63) / 64.0f);
    float ta = t[g] * tf;
    float v = (tid < 64) ? cosf(ta) : sinf(ta);   // cos first
    __bf16 bv = (__bf16)v;
    #pragma unroll
    for (int nl = 0; nl < kNN; ++nl)
        tecat[((size_t)(g*kNN + nl))*384 + 256 + tid] = bv;
}

// ---------------- 64x64-tile bf16 GEMM: C = A[M][lda] @ W[N][ldw]^T ----------------
// EPI 0: Sb/D fp32 split (N=512): n<256 -> out0 = acc+bias, else out1 = acc
// EPI 2: outbf = bf16(silu(acc+bias))             (stride ldo)
// EPI 3: h += silu(acc+bias); write h fp32 + hcat bf16
// EPI 4: outbf = bf16(acc+bias)                   (stride ldo)
// EPI 5: h = acc+bias (init); write h fp32 + hcat bf16
template<int K, int EPI>
__global__ __launch_bounds__(256) void gemm64(
        const __bf16* __restrict__ A, int lda,
        const __bf16* __restrict__ W, int ldw,
        const float* __restrict__ bias,
        float* __restrict__ out0, float* __restrict__ out1,
        __bf16* __restrict__ outbf, int ldo,
        float* __restrict__ hmaster, __bf16* __restrict__ hcat) {
    constexpr int NC = K / 32;
    __shared__ __bf16 As[2][64*40];
    __shared__ __bf16 Bs[2][64*40];
    int tid = threadIdx.x;
    int lane = tid & 63;
    int wid = tid >> 6;
    int wm = wid >> 1, wn = wid & 1;
    int r16 = lane & 15, g4 = lane >> 4;
    int mbase = blockIdx.x * 64;
    int nbase = blockIdx.y * 64;
    int srow = tid >> 2, sseg = tid & 3;
    const __bf16* agp = A + (size_t)(mbase + srow)*lda + sseg*8;
    const __bf16* wgp = W + (size_t)(nbase + srow)*ldw + sseg*8;
    int woff = srow*40 + sseg*8;

    f32x4 acc[2][2] = {};
    uint4 ra, rb;
    ra = *(const uint4*)(agp);
    rb = *(const uint4*)(wgp);
    *(uint4*)&As[0][woff] = ra;
    *(uint4*)&Bs[0][woff] = rb;
    __syncthreads();
    for (int c = 0; c < NC; ++c) {
        int cur = c & 1;
        if (c + 1 < NC) {
            ra = *(const uint4*)(agp + (c+1)*32);
            rb = *(const uint4*)(wgp + (c+1)*32);
        }
        bf16x8 af[2], bfg[2];
        #pragma unroll
        for (int mt = 0; mt < 2; ++mt)
            af[mt] = *(const bf16x8*)&As[cur][(wm*32 + mt*16 + r16)*40 + g4*8];
        #pragma unroll
        for (int nt = 0; nt < 2; ++nt)
            bfg[nt] = *(const bf16x8*)&Bs[cur][(wn*32 + nt*16 + r16)*40 + g4*8];
        #pragma unroll
        for (int mt = 0; mt < 2; ++mt)
            #pragma unroll
            for (int nt = 0; nt < 2; ++nt)
                acc[mt][nt] = __builtin_amdgcn_mfma_f32_16x16x32_bf16(af[mt], bfg[nt], acc[mt][nt], 0, 0, 0);
        if (c + 1 < NC) {
            int nxt = cur ^ 1;
            *(uint4*)&As[nxt][woff] = ra;
            *(uint4*)&Bs[nxt][woff] = rb;
        }
        __syncthreads();
    }
    #pragma unroll
    for (int mt = 0; mt < 2; ++mt)
        #pragma unroll
        for (int nt = 0; nt < 2; ++nt) {
            int n = nbase + wn*32 + nt*16 + r16;
            #pragma unroll
            for (int r = 0; r < 4; ++r) {
                int m = mbase + wm*32 + mt*16 + g4*4 + r;
                float v = acc[mt][nt][r];
                if (EPI == 0) {
                    if (n < 256) out0[(size_t)m*256 + n] = v + bias[n];
                    else         out1[(size_t)m*256 + (n - 256)] = v;
                } else if (EPI == 2) {
                    outbf[(size_t)m*ldo + n] = (__bf16)fsilu(v + bias[n]);
                } else if (EPI == 3) {
                    float hv = hmaster[(size_t)m*256 + n] + fsilu(v + bias[n]);
                    hmaster[(size_t)m*256 + n] = hv;
                    hcat[(size_t)m*512 + n] = (__bf16)hv;
                } else if (EPI == 4) {
                    outbf[(size_t)m*ldo + n] = (__bf16)(v + bias[n]);
                } else if (EPI == 5) {
                    float hv = v + bias[n];
                    hmaster[(size_t)m*256 + n] = hv;
                    hcat[(size_t)m*512 + n] = (__bf16)hv;
                }
            }
        }
}

// ------------- fused edge kernel (R8-measured best): block = 128 edges (4 srcs) --------
// feats in REGISTERS; fp32 Ds/Ss in LDS; staged W1s/W2s; 3 barriers per nc-chunk.
__global__ __launch_bounds__(256, 2) void fused_edge(
        const float* __restrict__ Sb, const float* __restrict__ Dq,
        const __bf16* __restrict__ fb, const __bf16* __restrict__ w1c,
        const __bf16* __restrict__ w2, const float* __restrict__ b2,
        __bf16* __restrict__ hcat) {
    __shared__ float  Ds[32][260];    // 33.3 KB
    __shared__ float  Ss[4][260];     // 4.2 KB
    __shared__ __bf16 W1s[32][112];   // 7.2 KB
    __shared__ __bf16 W2s[256][40];   // 20.5 KB
    __shared__ __bf16 As_[128][40];   // 10.2 KB

    int tid = threadIdx.x;
    int lane = tid & 63;
    int w = tid >> 6;                 // wave: owns edges w*32..w*32+31 (src s0+w)
    int r16 = lane & 15, g4 = lane >> 4;
    int ebase = blockIdx.x * 128;
    int graph = ebase >> 10;
    int s0 = ebase >> 5;

    // feats -> registers: rows {w*32+r16, w*32+16+r16}, cols g4*8, 3 k-chunks
    bf16x8 fReg[2][3];
    #pragma unroll
    for (int half = 0; half < 2; ++half) {
        const __bf16* fp = fb + (size_t)(ebase + w*32 + half*16 + r16)*kKF + g4*8;
        #pragma unroll
        for (int kc = 0; kc < 3; ++kc)
            fReg[half][kc] = *(const bf16x8*)(fp + kc*32);
    }
    { // D rows [32][256] fp32
        int dl = tid >> 3, seg = tid & 7;
        const float4* src = (const float4*)(Dq + (size_t)(graph*32 + dl)*256 + seg*32);
        #pragma unroll
        for (int i = 0; i < 8; ++i)
            *(float4*)&Ds[dl][seg*32 + i*4] = src[i];
    }
    { // S rows [4][256]
        int sl = tid >> 6, c4 = (tid & 63) * 4;
        *(float4*)&Ss[sl][c4] = *(const float4*)(Sb + (size_t)(s0 + sl)*256 + c4);
    }
    __syncthreads();

    f32x4 acc2[2][16] = {};
    for (int nc = 0; nc < 8; ++nc) {
        __syncthreads();   // prev As_/W2s/W1s consumed
        if (tid < 128) {   // W1 chunk [32][96]: 4 threads/row, 3 uint4
            int row = tid >> 2, q = tid & 3;
            const uint4* src = (const uint4*)(w1c + (size_t)(nc*32 + row)*kKF + q*24);
            #pragma unroll
            for (int i = 0; i < 3; ++i)
                *(uint4*)&W1s[row][q*24 + i*8] = src[i];
        }
        #pragma unroll
        for (int p = 0; p < 4; ++p) {  // W2 chunk [256][32]
            int row = (tid >> 2) + p*64, q = tid & 3;
            *(uint4*)&W2s[row][q*8] = *(const uint4*)(w2 + (size_t)row*256 + nc*32 + q*8);
        }
        __syncthreads();   // staging ready

        // phase 1: F chunk = feats @ w1c_chunk^T
        f32x4 acc1[2][2] = {};
        #pragma unroll
        for (int kc = 0; kc < 3; ++kc) {
            bf16x8 bg0 = *(const bf16x8*)&W1s[r16][kc*32 + g4*8];
            bf16x8 bg1 = *(const bf16x8*)&W1s[16 + r16][kc*32 + g4*8];
            acc1[0][0] = __builtin_amdgcn_mfma_f32_16x16x32_bf16(fReg[0][kc], bg0, acc1[0][0], 0, 0, 0);
            acc1[0][1] = __builtin_amdgcn_mfma_f32_16x16x32_bf16(fReg[0][kc], bg1, acc1[0][1], 0, 0, 0);
            acc1[1][0] = __builtin_amdgcn_mfma_f32_16x16x32_bf16(fReg[1][kc], bg0, acc1[1][0], 0, 0, 0);
            acc1[1][1] = __builtin_amdgcn_mfma_f32_16x16x32_bf16(fReg[1][kc], bg1, acc1[1][1], 0, 0, 0);
        }
        // A-build: silu(F + S + D) -> As_
        #pragma unroll
        for (int nt = 0; nt < 2; ++nt) {
            int lc = nt*16 + r16;
            int n  = nc*32 + lc;
            float sv = Ss[w][n];
            #pragma unroll
            for (int mt = 0; mt < 2; ++mt)
                #pragma unroll
                for (int r = 0; r < 4; ++r) {
                    int dl = mt*16 + g4*4 + r;
                    float v = acc1[mt][nt][r] + sv + Ds[dl][n];
                    As_[w*32 + dl][lc] = (__bf16)fsilu(v);
                }
        }
        __syncthreads();   // As_ ready

        // phase 2
        bf16x8 am0 = *(const bf16x8*)&As_[w*32 + r16][g4*8];
        bf16x8 am1 = *(const bf16x8*)&As_[w*32 + 16 + r16][g4*8];
        #pragma unroll
        for (int nt = 0; nt < 16; ++nt) {
            bf16x8 bv = *(const bf16x8*)&W2s[nt*16 + r16][g4*8];
            acc2[0][nt] = __builtin_amdgcn_mfma_f32_16x16x32_bf16(am0, bv, acc2[0][nt], 0, 0, 0);
            acc2[1][nt] = __builtin_amdgcn_mfma_f32_16x16x32_bf16(am1, bv, acc2[1][nt], 0, 0, 0);
        }
    }

    // epilogue: mean over the wave's 32 edges of silu(acc2 + b2)
    const float inv32 = 1.0f / 32.0f;
    #pragma unroll
    for (int nt = 0; nt < 16; ++nt) {
        int col = nt*16 + r16;
        float bb = b2[col];
        float p = 0.f;
        #pragma unroll
        for (int r = 0; r < 4; ++r)
            p += fsilu(acc2[0][nt][r] + bb) + fsilu(acc2[1][nt][r] + bb);
        p += __shfl_xor(p, 16);
        p += __shfl_xor(p, 32);
        if (lane < 16)
            hcat[(size_t)(s0 + w)*512 + 256 + col] = (__bf16)(p * inv32);
    }
}

// ---------------- heads ----------------
__global__ void coord_equiv_kernel(const float* __restrict__ h,
                                   const float* __restrict__ coord_w,
                                   const float* __restrict__ G,
                                   const int* __restrict__ invp,
                                   float* __restrict__ out_x) {
    int b = blockIdx.x;
    int tid = threadIdx.x; // 128
    __shared__ float cd[kNN][4];
    if (tid < kNN*3) {
        int nl = tid / 3, j = tid - nl*3;
        const float* hr = h + (size_t)(b*kNN + nl)*kH;
        const float* wr = coord_w + (size_t)j*kH;
        float acc = 0.f;
        #pragma unroll 4
        for (int k = 0; k < kH; ++k) acc += hr[k]*wr[k];
        cd[nl][j] = acc;
    }
    __syncthreads();
    if (tid < kNN*3) {
        int nl = tid / 3, j = tid - nl*3;
        float acc = 0.f;
        for (int g = 0; g < kGS; ++g) {
            int bg = b*kGS + g;
            int p = invp[bg*kNN + nl];
            const float* Gr = G + (size_t)bg*16 + j*4;
            acc += cd[p][0]*Gr[0] + cd[p][1]*Gr[1] + cd[p][2]*Gr[2] + Gr[3];
        }
        out_x[(size_t)(b*kNN + nl)*3 + j] = acc * (1.0f/kGS);
    }
}

__global__ void graphfeat_kernel(const float* __restrict__ h,
                                 const float* __restrict__ lattice_w,
                                 float* __restrict__ out_lat) {
    int g = blockIdx.x;
    int c = threadIdx.x;
    __shared__ float gf[kH];
    float s = 0.f;
    for (int nl = 0; nl < kNN; ++nl) s += h[(size_t)(g*kNN + nl)*kH + c];
    gf[c] = s * (1.0f/kNN);
    __syncthreads();
    if (c < 6) {
        const float* wr = lattice_w + (size_t)c*kH;
        float acc = 0.f;
        #pragma unroll 4
        for (int k = 0; k < kH; ++k) acc += gf[k]*wr[k];
        out_lat[g*6 + c] = acc;
    }
}

} // namespace

extern "C" void kernel_launch(void* const* d_in, const int* in_sizes, int n_in,
                              void* d_out, int out_size, void* d_ws, size_t ws_size,
                              hipStream_t stream) {
    (void)in_sizes; (void)n_in; (void)out_size; (void)ws_size;
    const float* t         = (const float*)d_in[0];
    const float* atom      = (const float*)d_in[1];
    const float* frac      = (const float*)d_in[2];
    const float* lattices  = (const float*)d_in[3];
    const float* G         = (const float*)d_in[4];
    const float* k_mean    = (const float*)d_in[5];
    const float* k_std     = (const float*)d_in[6];
    const float* k_mask    = (const float*)d_in[7];
    const float* k_bias    = (const float*)d_in[8];
    const float* emb_w     = (const float*)d_in[9];
    const float* emb_b     = (const float*)d_in[10];
    const float* latent_w  = (const float*)d_in[11];
    const float* latent_b  = (const float*)d_in[12];
    const float* edge_w1   = (const float*)d_in[13];
    const float* edge_b1   = (const float*)d_in[14];
    const float* edge_w2   = (const float*)d_in[15];
    const float* edge_b2   = (const float*)d_in[16];
    const float* node_w1   = (const float*)d_in[17];
    const float* node_b1   = (const float*)d_in[18];
    const float* node_w2   = (const float*)d_in[19];
    const float* node_b2   = (const float*)d_in[20];
    const float* coord_w   = (const float*)d_in[21];
    const float* lattice_w = (const float*)d_in[22];
    const int*   invp      = (const int*)d_in[25];

    float* out_x   = (float*)d_out;            // [4096,3]
    float* out_lat = (float*)d_out + kN*3;     // [128,6]

    char* base = (char*)d_ws;
    size_t off = 0;
    auto carve = [&](size_t bytes) { char* p = base + off; off += bytes; return p; };
    float*  ltl    = (float*)carve(8192);
    float*  h      = (float*)carve(4194304);          // [4096][256] fp32
    float*  Sbuf   = (float*)carve(4194304);          // [4096][256] fp32: S + b1
    float*  Dbuf   = (float*)carve(4194304);          // [4096][256] fp32: D
    __bf16* hcat   = (__bf16*)carve(4194304);         // [4096][512] bf16: [h | agg]
    __bf16* t1     = (__bf16*)carve(2097152);         // [4096][256] bf16
    __bf16* fb     = (__bf16*)carve(25165824);        // feats bf16 [131072][96]
    __bf16* w1ab   = (__bf16*)carve(1048576);         // [L][512][256]
    __bf16* w1c    = (__bf16*)carve(262144);          // [L][256][96]
    __bf16* w2b    = (__bf16*)carve(524288);          // [L][256][256]
    __bf16* nw1b   = (__bf16*)carve(1048576);         // [L][256][512]
    __bf16* nw2b   = (__bf16*)carve(524288);          // [L][256][256]
    __bf16* at_bf  = (__bf16*)carve(1048576);         // [4096][128] atom bf16 padded
    __bf16* embwb  = (__bf16*)carve(65536);           // [256][128]
    __bf16* latwb  = (__bf16*)carve(196608);          // [256][384]
    __bf16* tecat  = (__bf16*)carve(3145728);         // [4096][384]: [h0 | temb]

    lattice_kernel<<<1, 128, 0, stream>>>(lattices, k_mean, k_std, k_mask, k_bias, ltl);
    feats_bf_kernel<<<kE/256, 256, 0, stream>>>(frac, lattices, ltl, fb);
    conv_all<<<(kConvTotal + 255)/256, 256, 0, stream>>>(
        edge_w1, edge_w2, node_w1, node_w2, atom, emb_w, latent_w,
        w1ab, w1c, w2b, nw1b, nw2b, at_bf, embwb, latwb);
    temb_kernel<<<kB, 128, 0, stream>>>(t, tecat);

    // embed GEMM1: h0 = at_bf[4096,128] @ embwb[256,128]^T + emb_b -> tecat[:, :256]
    gemm64<128, 4><<<dim3(64, 4), 256, 0, stream>>>(
        at_bf, 128, embwb, 128, emb_b,
        nullptr, nullptr, tecat, 384, nullptr, nullptr);
    // embed GEMM2: h = tecat[4096,384] @ latwb[256,384]^T + latent_b -> h fp32 + hcat bf16
    gemm64<384, 5><<<dim3(64, 4), 256, 0, stream>>>(
        tecat, 384, latwb, 384, latent_b,
        nullptr, nullptr, nullptr, 0, h, hcat);

    for (int l = 0; l < kL; ++l) {
        // S/D: [4096,256(of 512)] @ w1ab[512][256]^T -> fp32 Sbuf(+b1), Dbuf
        gemm64<256, 0><<<dim3(64, 8), 256, 0, stream>>>(
            hcat, 512, w1ab + (size_t)l*512*256, 256,
            edge_b1 + l*256, Sbuf, Dbuf, nullptr, 0, nullptr, nullptr);
        // fused edge path: Fproj + A-build + GEMM2 + scatter-mean agg
        fused_edge<<<1024, 256, 0, stream>>>(
            Sbuf, Dbuf, fb, w1c + (size_t)l*256*kKF,
            w2b + (size_t)l*256*256, edge_b2 + l*256, hcat);
        // node MLP
        gemm64<512, 2><<<dim3(64, 4), 256, 0, stream>>>(
            hcat, 512, nw1b + (size_t)l*256*512, 512,
            node_b1 + l*256, nullptr, nullptr, t1, 256, nullptr, nullptr);
        gemm64<256, 3><<<dim3(64, 4), 256, 0, stream>>>(
            t1, 256, nw2b + (size_t)l*256*256, 256,
            node_b2 + l*256, nullptr, nullptr, nullptr, 0, h, hcat);
    }
    coord_equiv_kernel<<<kB, 128, 0, stream>>>(h, coord_w, G, invp, out_x);
    graphfeat_kernel<<<kB, 256, 0, stream>>>(h, lattice_w, out_lat);
}